// Round 6
// baseline (475.358 us; speedup 1.0000x reference)
//
#include <hip/hip_runtime.h>
#include <hip/hip_bf16.h>
#include <math.h>

// Problem constants
#define S_LEN 2048
#define HIDDEN 4096
#define N_HEADS 32
#define N_KV 8
#define HEAD_DIM 128

typedef __attribute__((ext_vector_type(8))) short short8;   // 8 bf16 = 4 VGPRs
typedef __attribute__((ext_vector_type(4))) float f32x4;    // MFMA C/D frag

typedef __attribute__((address_space(3))) unsigned int as3_u32;
typedef const __attribute__((address_space(1))) unsigned int as1_u32;

__device__ __forceinline__ void gload16(const void* g, void* lds) {
  __builtin_amdgcn_global_load_lds((as1_u32*)g, (as3_u32*)lds, 16, 0, 0);
}

__device__ __forceinline__ unsigned short f2bf(float f) {
  unsigned int u = __float_as_uint(f);
  return (unsigned short)((u + 0x7fff + ((u >> 16) & 1)) >> 16);  // RNE
}
__device__ __forceinline__ float bf2f(unsigned short u) {
  return __uint_as_float(((unsigned int)u) << 16);
}

__device__ __forceinline__ void storeC(float* C, float v) { *C = v; }
__device__ __forceinline__ void storeC(unsigned short* C, float v) { *C = f2bf(v); }

// ---------------------------------------------------------------------------
// Fused fp32 -> bf16 conversion of the 4 pre-QKV tensors (1 launch, was 4).
// Element counts: X 8388608 | Wq 16777216 | Wk 4194304 | Wv 4194304.
// ---------------------------------------------------------------------------
__global__ __launch_bounds__(256) void conv4(
    const float* __restrict__ X, const float* __restrict__ Wq,
    const float* __restrict__ Wk, const float* __restrict__ Wv,
    unsigned short* __restrict__ Xb, unsigned short* __restrict__ Wqb,
    unsigned short* __restrict__ Wkb, unsigned short* __restrict__ Wvb) {
  size_t i = ((size_t)blockIdx.x * 256 + threadIdx.x) * 4;
  const float* src; unsigned short* dst; size_t off;
  if (i < 8388608UL)       { src = X;  dst = Xb;  off = i; }
  else if (i < 25165824UL) { src = Wq; dst = Wqb; off = i - 8388608UL; }
  else if (i < 29360128UL) { src = Wk; dst = Wkb; off = i - 25165824UL; }
  else                     { src = Wv; dst = Wvb; off = i - 29360128UL; }
  float4 v = *(const float4*)&src[off];
  ushort4 o;
  o.x = f2bf(v.x); o.y = f2bf(v.y); o.z = f2bf(v.z); o.w = f2bf(v.w);
  *(ushort4*)&dst[off] = o;
}

#define BN 128

// ---------------------------------------------------------------------------
// gemm_qkv v3: 128x128 C-tile, 256 threads (4 waves, 64x64/wave = m97's
// 16 MFMA : 8 ds_read ratio), BK=32, TRIPLE-buffered LDS (3 x 16 KB = 48 KB)
// -> 3 blocks/CU, grid (48,16) = 768 = 3 x 256 CUs: PERFECTLY BALANCED.
// Round-5 root cause: 384 blocks over 512 slots -> half the CUs carried 2
// blocks, half 1; makespan = heavy CUs (4.5 TF/CU => ~89 us if uniform).
// Same verified discipline: stage t+2 while computing t (triple buffer =>
// write never touches a read buffer), counted vmcnt(4) (4 gloads/tile/lane,
// FIFO => t+1 resident), source-XOR swizzle p^(r&3), setprio around MFMA.
// ---------------------------------------------------------------------------
#define BK2 32
#define NKT2 (HIDDEN / BK2)   // 128 K-tiles

__global__ __launch_bounds__(256, 3) void gemm_qkv(
    const unsigned short* __restrict__ Xb,
    const unsigned short* __restrict__ Wqb, const unsigned short* __restrict__ Wkb,
    const unsigned short* __restrict__ Wvb,
    unsigned short* __restrict__ Qb, unsigned short* __restrict__ Kb,
    unsigned short* __restrict__ Vb) {
  const int colBase = blockIdx.x * BN;
  const int rowBase = blockIdx.y * 128;
  const unsigned short* Bw;
  unsigned short* Cb;
  int ldc, ccol;
  if (colBase < 4096)      { Bw = Wqb + (size_t)colBase * HIDDEN;          Cb = Qb; ldc = 4096; ccol = colBase; }
  else if (colBase < 5120) { Bw = Wkb + (size_t)(colBase - 4096) * HIDDEN; Cb = Kb; ldc = 1024; ccol = colBase - 4096; }
  else                     { Bw = Wvb + (size_t)(colBase - 5120) * HIDDEN; Cb = Vb; ldc = 1024; ccol = colBase - 5120; }
  const unsigned short* A = Xb + (size_t)rowBase * HIDDEN;
  unsigned short* C = Cb + (size_t)rowBase * ldc + ccol;

  __shared__ unsigned short Abuf[3][128 * BK2];   // 3 x 8 KB
  __shared__ unsigned short Bbuf[3][BN * BK2];    // 3 x 8 KB

  const int tid = threadIdx.x;
  const int w = tid >> 6;          // 0..3
  const int lane = tid & 63;
  const int lrow = lane & 15;
  const int lk8 = lane >> 4;       // 0..3 (k-chunk within 32-K row)
  const int wr = (w >> 1) * 64;    // wave M base: 0,64
  const int wc = (w & 1) * 64;     // wave N base: 0,64
  const int lr16 = lane >> 2;      // staging: row within 16-row segment
  const int lp = lane & 3;         // staging: chunk position 0..3

  f32x4 acc[4][4];
#pragma unroll
  for (int i = 0; i < 4; i++)
#pragma unroll
    for (int j = 0; j < 4; j++) acc[i][j] = (f32x4){0.f, 0.f, 0.f, 0.f};

  // Stage one 1 KB segment (16 rows x 4 chunks of 16 B): LDS linear, source
  // swizzled: LDS chunk (r, p) holds global chunk (r, p ^ (r&3)).
#define STAGE_A2(bi, t, g) {                                                   \
    int seg = (g) * 4 + w;                     /* 0..7 */                      \
    int r = seg * 16 + lr16;                                                   \
    int c = lp ^ (r & 3);                                                      \
    gload16(&A[(size_t)r * HIDDEN + (t) * BK2 + c * 8], &Abuf[bi][seg * 512]); \
  }
#define STAGE_B2(bi, t, g) {                                                   \
    int seg = (g) * 4 + w;                     /* 0..7 */                      \
    int r = seg * 16 + lr16;                                                   \
    int c = lp ^ (r & 3);                                                      \
    gload16(&Bw[(size_t)r * HIDDEN + (t) * BK2 + c * 8], &Bbuf[bi][seg * 512]);\
  }
  // Fragment read: global chunk (r, lk8) sits at LDS chunk lk8 ^ (r&3).
#define RD_FRAG2(buf, rbase)                                                   \
  (*(const short8*)&(buf)[((rbase) + lrow) * 32 + ((lk8) ^ (((rbase) + lrow) & 3)) * 8])

  // ---- prologue: stage tiles 0 and 1 (4 loads/lane each) ----
  STAGE_A2(0, 0, 0); STAGE_A2(0, 0, 1); STAGE_B2(0, 0, 0); STAGE_B2(0, 0, 1);
  STAGE_A2(1, 1, 0); STAGE_A2(1, 1, 1); STAGE_B2(1, 1, 0); STAGE_B2(1, 1, 1);
  asm volatile("s_waitcnt vmcnt(4)" ::: "memory");  // tile0 resident
  __builtin_amdgcn_s_barrier();

  for (int t = 0; t < NKT2; t++) {
    const int bi = t % 3;
    const int bs = (t + 2) % 3;
    const bool st = (t + 2) < NKT2;
    const unsigned short* Ac = Abuf[bi];
    const unsigned short* Bc = Bbuf[bi];

    short8 afr[4], bfr[4];
#pragma unroll
    for (int m = 0; m < 4; m++) afr[m] = RD_FRAG2(Ac, wr + m * 16);
#pragma unroll
    for (int n = 0; n < 4; n++) bfr[n] = RD_FRAG2(Bc, wc + n * 16);
    if (st) { STAGE_A2(bs, t + 2, 0); STAGE_A2(bs, t + 2, 1);
              STAGE_B2(bs, t + 2, 0); STAGE_B2(bs, t + 2, 1); }
    __builtin_amdgcn_s_barrier();
    __builtin_amdgcn_s_setprio(1);
#pragma unroll
    for (int m = 0; m < 4; m++)
#pragma unroll
      for (int n = 0; n < 4; n++)
        acc[m][n] = __builtin_amdgcn_mfma_f32_16x16x32_bf16(afr[m], bfr[n], acc[m][n], 0, 0, 0);
    __builtin_amdgcn_s_setprio(0);
    if (st) asm volatile("s_waitcnt vmcnt(4)" ::: "memory");
    else    asm volatile("s_waitcnt vmcnt(0)" ::: "memory");
    __builtin_amdgcn_s_barrier();
  }
#undef STAGE_A2
#undef STAGE_B2
#undef RD_FRAG2

#pragma unroll
  for (int i = 0; i < 4; i++)
#pragma unroll
    for (int j = 0; j < 4; j++) {
      int col = wc + j * 16 + lrow;
#pragma unroll
      for (int r = 0; r < 4; r++) {
        int row = wr + i * 16 + lk8 * 4 + r;
        storeC(&C[(size_t)row * ldc + col], acc[i][j][r]);
      }
    }
}

// ---------------------------------------------------------------------------
// gemm_out (round-4 verified, unchanged): 256x128, BK=64, triple buffer
// 144 KB, 256 blocks = exact CU fill.
// ---------------------------------------------------------------------------
#define BM 256
#define BK 64
#define NKT (HIDDEN / BK)   // 64 K-tiles

__global__ __launch_bounds__(512, 2) void gemm_out(
    const unsigned short* __restrict__ Ob, const unsigned short* __restrict__ Wob,
    float* __restrict__ C_) {
  const int colBase = blockIdx.x * BN;
  const int rowBase = blockIdx.y * BM;
  const unsigned short* A = Ob + (size_t)rowBase * HIDDEN;
  const unsigned short* B = Wob + (size_t)colBase * HIDDEN;
  float* C = C_ + (size_t)rowBase * HIDDEN + colBase;
  const int ldc = HIDDEN;

  __shared__ unsigned short Abuf[3][BM * BK];   // 3 x 32 KB
  __shared__ unsigned short Bbuf[3][BN * BK];   // 3 x 16 KB

  const int tid = threadIdx.x;
  const int w = tid >> 6;
  const int lane = tid & 63;
  const int lrow = lane & 15;
  const int lk8 = lane >> 4;
  const int wr = (w >> 1) * 64;
  const int wc = (w & 1) * 64;
  const int lr8 = lane >> 3;
  const int lp = lane & 7;

  f32x4 acc[4][4];
#pragma unroll
  for (int i = 0; i < 4; i++)
#pragma unroll
    for (int j = 0; j < 4; j++) acc[i][j] = (f32x4){0.f, 0.f, 0.f, 0.f};

#define STAGE_A(bi, t, g) {                                                  \
    int seg = (g) * 8 + w;                                                   \
    int r = seg * 8 + lr8;                                                   \
    int c = lp ^ (r & 7);                                                    \
    gload16(&A[(size_t)r * HIDDEN + (t) * BK + c * 8], &Abuf[bi][seg * 512]);\
  }
#define STAGE_B(bi, t, g) {                                                  \
    int seg = (g) * 8 + w;                                                   \
    int r = seg * 8 + lr8;                                                   \
    int c = lp ^ (r & 7);                                                    \
    gload16(&B[(size_t)r * HIDDEN + (t) * BK + c * 8], &Bbuf[bi][seg * 512]);\
  }
#define RD_FRAG(buf, rbase, ks)                                              \
  (*(const short8*)&(buf)[((rbase) + lrow) * 64 + (((ks) * 4 + lk8) ^ (((rbase) + lrow) & 7)) * 8])

#pragma unroll
  for (int g = 0; g < 4; g++) STAGE_A(0, 0, g);
#pragma unroll
  for (int g = 0; g < 2; g++) STAGE_B(0, 0, g);
#pragma unroll
  for (int g = 0; g < 4; g++) STAGE_A(1, 1, g);
#pragma unroll
  for (int g = 0; g < 2; g++) STAGE_B(1, 1, g);
  asm volatile("s_waitcnt vmcnt(6)" ::: "memory");
  __builtin_amdgcn_s_barrier();

  for (int t = 0; t < NKT; t++) {
    const int bi = t % 3;
    const int bs = (t + 2) % 3;
    const bool st = (t + 2) < NKT;
    const unsigned short* Ac = Abuf[bi];
    const unsigned short* Bc = Bbuf[bi];

    short8 bfr[4][2], afr[2][2];

#pragma unroll
    for (int n = 0; n < 4; n++)
#pragma unroll
      for (int ks = 0; ks < 2; ks++)
        bfr[n][ks] = RD_FRAG(Bc, wc + n * 16, ks);
#pragma unroll
    for (int m = 0; m < 2; m++)
#pragma unroll
      for (int ks = 0; ks < 2; ks++)
        afr[m][ks] = RD_FRAG(Ac, wr + m * 16, ks);
    if (st) { STAGE_A(bs, t + 2, 0); STAGE_A(bs, t + 2, 1); STAGE_B(bs, t + 2, 0); }
    __builtin_amdgcn_s_barrier();
    __builtin_amdgcn_s_setprio(1);
#pragma unroll
    for (int m = 0; m < 2; m++)
#pragma unroll
      for (int n = 0; n < 4; n++)
#pragma unroll
        for (int ks = 0; ks < 2; ks++)
          acc[m][n] = __builtin_amdgcn_mfma_f32_16x16x32_bf16(afr[m][ks], bfr[n][ks], acc[m][n], 0, 0, 0);
    __builtin_amdgcn_s_setprio(0);
    __builtin_amdgcn_s_barrier();

#pragma unroll
    for (int m = 0; m < 2; m++)
#pragma unroll
      for (int ks = 0; ks < 2; ks++)
        afr[m][ks] = RD_FRAG(Ac, wr + (m + 2) * 16, ks);
    if (st) { STAGE_A(bs, t + 2, 2); STAGE_A(bs, t + 2, 3); STAGE_B(bs, t + 2, 1); }
    __builtin_amdgcn_s_barrier();
    __builtin_amdgcn_s_setprio(1);
#pragma unroll
    for (int m = 0; m < 2; m++)
#pragma unroll
      for (int n = 0; n < 4; n++)
#pragma unroll
        for (int ks = 0; ks < 2; ks++)
          acc[m + 2][n] = __builtin_amdgcn_mfma_f32_16x16x32_bf16(afr[m][ks], bfr[n][ks], acc[m + 2][n], 0, 0, 0);
    __builtin_amdgcn_s_setprio(0);
    if (st) asm volatile("s_waitcnt vmcnt(6)" ::: "memory");
    else    asm volatile("s_waitcnt vmcnt(0)" ::: "memory");
    __builtin_amdgcn_s_barrier();
  }
#undef STAGE_A
#undef STAGE_B
#undef RD_FRAG

#pragma unroll
  for (int i = 0; i < 4; i++)
#pragma unroll
    for (int j = 0; j < 4; j++) {
      int col = wc + j * 16 + lrow;
#pragma unroll
      for (int r = 0; r < 4; r++) {
        int row = wr + i * 16 + lk8 * 4 + r;
        storeC(&C[(size_t)row * ldc + col], acc[i][j][r]);
      }
    }
}

// ---------------------------------------------------------------------------
// Fused post-QKV prep (1 launch, was 3):
//   blocks [0, 20480): RoPE on Q/K -> packed Qp/Kp (Q pre-scaled exp2 domain)
//   blocks [20480, 20992): V transpose -> packed Vp tiles
//   blocks [20992, 37376): Wo fp32 -> bf16 (into Wqb space, dead after qkv)
// All three are independent and depend only on gemm_qkv (Wo conv on nothing).
// ---------------------------------------------------------------------------
#define QSCALE 0.12753102123752056f  // 0.08838834764831845 * 1.4426950408889634
#define ROPE_BLOCKS 20480
#define TR_BLOCKS 512

__global__ __launch_bounds__(256) void prep_fused(
    const unsigned short* __restrict__ Qb, const unsigned short* __restrict__ Kb,
    const unsigned short* __restrict__ Vb,
    unsigned short* __restrict__ Qp, unsigned short* __restrict__ Kp,
    unsigned short* __restrict__ Vp,
    const float* __restrict__ Wo, unsigned short* __restrict__ Wob) {
  __shared__ unsigned short t[64][72];
  const int tid = threadIdx.x;
  int bx = blockIdx.x;

  if (bx < ROPE_BLOCKS) {
    // ---- RoPE ----
    int idx = bx * 256 + tid;
    int d = idx & 63;
    int sh = idx >> 6;
    int h = sh % (N_HEADS + N_KV);
    int s = sh / (N_HEADS + N_KV);
    if (s >= S_LEN) return;

    float freq = expf(-(float)d * (9.210340371976184f / 64.0f));
    float ang = (float)s * freq;
    float sn, cs;
    sincosf(ang, &sn, &cs);

    const unsigned short* src;
    unsigned short* dst;
    float sc_out;
    if (h < N_HEADS) {
      src = Qb + ((size_t)s * N_HEADS + h) * HEAD_DIM;
      dst = Qp + (((size_t)h * 128 + (s >> 4)) * 16 + (s & 15)) * HEAD_DIM;
      sc_out = QSCALE;
    } else {
      int kvh = h - N_HEADS;
      src = Kb + ((size_t)s * N_KV + kvh) * HEAD_DIM;
      dst = Kp + (((size_t)kvh * 32 + (s >> 6)) * 64 + (s & 63)) * HEAD_DIM;
      sc_out = 1.0f;
    }

    float x1 = bf2f(src[d]);
    float x2 = bf2f(src[d + 64]);
    dst[d] = f2bf((x1 * cs - x2 * sn) * sc_out);
    dst[d + 64] = f2bf((x2 * cs + x1 * sn) * sc_out);
    return;
  }
  bx -= ROPE_BLOCKS;

  if (bx < TR_BLOCKS) {
    // ---- V transpose (flattened from dim3(32,16)) ----
    const int s0 = (bx & 31) * 64;   // key tile base
    const int c0 = (bx >> 5) * 64;   // flat dim base (kvh*128 + d)
    const int kt = s0 >> 6;
#pragma unroll
    for (int i = 0; i < 2; i++) {
      int c = tid + i * 256;
      int r = c >> 3, ch = c & 7;
      *(short8*)&t[r][ch * 8] = *(const short8*)&Vb[(size_t)(s0 + r) * 1024 + c0 + ch * 8];
    }
    __syncthreads();
#pragma unroll
    for (int i = 0; i < 4; i++) {
      int c = tid + i * 256;
      int orow = c >> 4, oc4 = (c & 15) * 4;
      int g = c0 + orow;               // flat dim
      int kvh = g >> 7, d = g & 127;
      ushort4 o;
      o.x = t[oc4 + 0][orow]; o.y = t[oc4 + 1][orow];
      o.z = t[oc4 + 2][orow]; o.w = t[oc4 + 3][orow];
      *(ushort4*)&Vp[(((size_t)kvh * 32 + kt) * 128 + d) * 64 + oc4] = o;
    }
    return;
  }
  bx -= TR_BLOCKS;

  // ---- Wo conv (16777216 elements) ----
  size_t i = ((size_t)bx * 256 + tid) * 4;
  float4 v = *(const float4*)&Wo[i];
  ushort4 o;
  o.x = f2bf(v.x); o.y = f2bf(v.y); o.z = f2bf(v.z); o.w = f2bf(v.w);
  *(ushort4*)&Wob[i] = o;
}

// ---------------------------------------------------------------------------
// MFMA flash attention v5: occupancy-doubled (round-3 verified, unchanged).
// Block = 64 queries x 1 head, 4 waves x 16 queries. K-tiles of 64.
// Grid 1024 -> 4 blocks/CU (LDS 40 KB), 16 waves/CU.
// ---------------------------------------------------------------------------
#define AK 64

__global__ __launch_bounds__(256, 4) void attn_mfma(
    const unsigned short* __restrict__ Qp, const unsigned short* __restrict__ Kp,
    const unsigned short* __restrict__ Vp, unsigned short* __restrict__ Ob) {
  const int b = blockIdx.x;
  const int h = b & 31;
  const int j = b >> 5;
  const int qt = (b < 512) ? j : (47 - j);   // 0..31, paired for balance
  const int kvh = h >> 2;

  const int tid = threadIdx.x;
  const int w = tid >> 6;
  const int lane = tid & 63;
  const int lrow = lane & 15;
  const int lk8 = lane >> 4;

  __shared__ unsigned short Ks[64 * 128];    // 16 KB, swizzled
  __shared__ unsigned short Vts[128 * 64];   // 16 KB, swizzled
  __shared__ unsigned short Ps[4 * 16 * 64]; // 8 KB, wave-private, swizzled
  unsigned short* Pw = &Ps[w * 16 * 64];

  // ---- Q fragments: wave w owns query strip qt*64 + w*16 .. +15 ----
  short8 qf[4];
  const int t0 = qt * 4 + w;                 // packed 16-query strip index
#pragma unroll
  for (int ks = 0; ks < 4; ks++)
    qf[ks] = *(const short8*)&Qp[(((size_t)h * 128 + t0) * 16 + lrow) * 128 +
                                 ks * 32 + lk8 * 8];

  f32x4 acc[8];  // O^T: [dim-tile], queries = lane&15
  float m_i = -1e30f, l_i = 0.f;
#pragma unroll
  for (int n = 0; n < 8; n++) acc[n] = (f32x4){0.f, 0.f, 0.f, 0.f};

  const int nkt = qt + 1;

  for (int kt = 0; kt < nkt; kt++) {
    const int kb = kt * AK;
    const unsigned short* Kt  = Kp + ((size_t)kvh * 32 + kt) * 8192;
    const unsigned short* Vtt = Vp + ((size_t)kvh * 32 + kt) * 8192;

    __syncthreads();  // all waves done reading previous tile
    // ---- Stage K + V^T (16 KB each) with swizzled contiguous sources ----
#pragma unroll
    for (int jj = 0; jj < 4; jj++) {
      int seg = w * 4 + jj;                 // 0..15, 1 KB LDS segment
      // K: lds slot (r = seg*4 + lk8, p = lrow) <- global chunk (r, p^(r&15))
      int kr = seg * 4 + lk8;
      int kc = lrow ^ (kr & 15);
      gload16(Kt + ((size_t)kr * 16 + kc) * 8, &Ks[seg * 512]);
      // Vt: lds slot (r = seg*8 + lane>>3, p = lane&7) <- chunk (r, p^(r&7))
      int vr = seg * 8 + (lane >> 3);
      int vc = (lane & 7) ^ (vr & 7);
      gload16(Vtt + ((size_t)vr * 8 + vc) * 8, &Vts[seg * 512]);
    }
    __syncthreads();  // barrier drains vmcnt -> staged data visible

    // ---- S^T = K Q^T ----
    f32x4 s[4];
#pragma unroll
    for (int n = 0; n < 4; n++) s[n] = (f32x4){0.f, 0.f, 0.f, 0.f};

#pragma unroll
    for (int ks = 0; ks < 4; ks++) {
      short8 kf[4];
#pragma unroll
      for (int n = 0; n < 4; n++)
        kf[n] = *(const short8*)&Ks[(n * 16 + lrow) * 128 + (((ks * 4 + lk8) ^ lrow)) * 8];
#pragma unroll
      for (int n = 0; n < 4; n++)
        s[n] = __builtin_amdgcn_mfma_f32_16x16x32_bf16(kf[n], qf[ks], s[n], 0, 0, 0);
    }

    // ---- Causal mask: rows=keys (lk8*4+r), cols=queries (lrow) ----
    const int wqb = qt * 64 + w * 16;
    if (kb + AK - 1 > wqb) {
      int query = wqb + lrow;
#pragma unroll
      for (int n = 0; n < 4; n++) {
        int keyb = kb + n * 16 + lk8 * 4;
#pragma unroll
        for (int r = 0; r < 4; r++)
          if (keyb + r > query) s[n][r] = -1e30f;
      }
    }

    // ---- Online softmax (exp2): 16 in-lane scores + 2 shuffles ----
    {
      float mx = -1e30f;
#pragma unroll
      for (int n = 0; n < 4; n++)
#pragma unroll
        for (int r = 0; r < 4; r++) mx = fmaxf(mx, s[n][r]);
      mx = fmaxf(mx, __shfl_xor(mx, 16, 64));
      mx = fmaxf(mx, __shfl_xor(mx, 32, 64));
      float mn = fmaxf(m_i, mx);
      float al = exp2f(m_i - mn);
      m_i = mn;
      float ls = 0.f;
#pragma unroll
      for (int n = 0; n < 4; n++)
#pragma unroll
        for (int r = 0; r < 4; r++) {
          float e = exp2f(s[n][r] - mn);
          s[n][r] = e;
          ls += e;
        }
      ls += __shfl_xor(ls, 16, 64);
      ls += __shfl_xor(ls, 32, 64);
      l_i = l_i * al + ls;
#pragma unroll
      for (int n = 0; n < 8; n++)
#pragma unroll
        for (int r = 0; r < 4; r++) acc[n][r] *= al;
    }

    // ---- P -> wave-private LDS [query][key], 16B-granular XOR swizzle ----
#pragma unroll
    for (int n = 0; n < 4; n++) {
      ushort4 pk;
      pk.x = f2bf(s[n][0]); pk.y = f2bf(s[n][1]);
      pk.z = f2bf(s[n][2]); pk.w = f2bf(s[n][3]);
      int c8 = n * 4 + lk8;                      // 8B chunk 0..15 in row
      int c16s = (c8 >> 1) ^ (lrow & 7);         // swizzled 16B slot
      *(ushort4*)&Pw[lrow * 64 + c16s * 8 + (c8 & 1) * 4] = pk;
    }

    // ---- O^T += V^T P^T ----
#pragma unroll
    for (int ks2 = 0; ks2 < 2; ks2++) {
      int c16s = (ks2 * 4 + lk8) ^ (lrow & 7);
      short8 pf = *(const short8*)&Pw[lrow * 64 + c16s * 8];
#pragma unroll
      for (int n = 0; n < 8; n++) {
        short8 vf = *(const short8*)&Vts[(n * 16 + lrow) * 64 +
                                         (((ks2 * 4 + lk8) ^ (lrow & 7))) * 8];
        acc[n] = __builtin_amdgcn_mfma_f32_16x16x32_bf16(vf, pf, acc[n], 0, 0, 0);
      }
    }
  }

  // ---- Epilogue: normalize, store O [s][h*128+d] ----
  {
    float inv = 1.0f / l_i;
    int row = qt * 64 + w * 16 + lrow;
#pragma unroll
    for (int n = 0; n < 8; n++) {
      ushort4 o;
      o.x = f2bf(acc[n][0] * inv); o.y = f2bf(acc[n][1] * inv);
      o.z = f2bf(acc[n][2] * inv); o.w = f2bf(acc[n][3] * inv);
      *(ushort4*)&Ob[(size_t)row * 4096 + h * 128 + n * 16 + lk8 * 4] = o;
    }
  }
}

// ---------------------------------------------------------------------------
extern "C" void kernel_launch(void* const* d_in, const int* in_sizes, int n_in,
                              void* d_out, int out_size, void* d_ws, size_t ws_size,
                              hipStream_t stream) {
  const float* X  = (const float*)d_in[0];
  const float* Wq = (const float*)d_in[1];
  const float* Wk = (const float*)d_in[2];
  const float* Wv = (const float*)d_in[3];
  const float* Wo = (const float*)d_in[4];
  float* out = (float*)d_out;

  char* p = (char*)d_ws;
  unsigned short* Qb  = (unsigned short*)p; p += (size_t)S_LEN * 4096 * 2;  // 16.8 MB
  unsigned short* Kb  = (unsigned short*)p; p += (size_t)S_LEN * 1024 * 2;  //  4.2 MB
  unsigned short* Vb  = (unsigned short*)p; p += (size_t)S_LEN * 1024 * 2;  //  4.2 MB
  unsigned short* Qp  = (unsigned short*)p; p += (size_t)S_LEN * 4096 * 2;  // 16.8 MB
  unsigned short* Kp  = (unsigned short*)p; p += (size_t)S_LEN * 1024 * 2;  //  4.2 MB
  unsigned short* Vp  = (unsigned short*)p; p += (size_t)S_LEN * 1024 * 2;  //  4.2 MB
  unsigned short* Xb  = (unsigned short*)p; p += (size_t)S_LEN * 4096 * 2;  // 16.8 MB
  unsigned short* Wqb = (unsigned short*)p; p += (size_t)4096 * 4096 * 2;   // 33.6 MB
  unsigned short* Wkb = (unsigned short*)p; p += (size_t)1024 * 4096 * 2;   //  8.4 MB
  unsigned short* Wvb = (unsigned short*)p; p += (size_t)1024 * 4096 * 2;   //  8.4 MB
  unsigned short* Ob  = Xb;   // Xb dead after gemm_qkv
  unsigned short* Wob = Wqb;  // Wqb dead after gemm_qkv

  // 1. fp32 -> bf16 for X, Wq, Wk, Wv (fused, 1 launch)
  conv4<<<32768, 256, 0, stream>>>(X, Wq, Wk, Wv, Xb, Wqb, Wkb, Wvb);

  // 2. Fused QKV projection -> bf16 (128x128, 768 blocks = 3/CU balanced)
  gemm_qkv<<<dim3(6144 / BN, S_LEN / 128), 256, 0, stream>>>(Xb, Wqb, Wkb, Wvb, Qb, Kb, Vb);

  // 3. RoPE + V transpose + Wo conv (fused, 1 launch)
  prep_fused<<<ROPE_BLOCKS + TR_BLOCKS + 16384, 256, 0, stream>>>(
      Qb, Kb, Vb, Qp, Kp, Vp, Wo, Wob);

  // 4. MFMA flash attention v5 -> bf16 (into Xb space), 64-query blocks
  attn_mfma<<<1024, 256, 0, stream>>>(Qp, Kp, Vp, Ob);

  // 5. Output projection (256 blocks = exact CU fill)
  gemm_out<<<dim3(4096 / BN, S_LEN / BM), 512, 0, stream>>>(Ob, Wob, out);
}